// Round 13
// baseline (264.111 us; speedup 1.0000x reference)
//
#include <hip/hip_runtime.h>
#include <cstdint>
#include <cstddef>

#define B_ 2048
#define S_ 168
#define NT_ 5376   // 128 groups x 42 t-tiles

// ---------- helpers ----------
typedef _Float16 h2_t __attribute__((ext_vector_type(2)));
typedef _Float16 f16x8 __attribute__((ext_vector_type(8)));
typedef float f32x4 __attribute__((ext_vector_type(4)));
typedef unsigned int u32;

__device__ __forceinline__ unsigned pack_h2f(float a, float b){
    h2_t v; v.x = (_Float16)a; v.y = (_Float16)b;
    return __builtin_bit_cast(unsigned, v);
}
__device__ __forceinline__ float fast_exp(float x){
    return __builtin_amdgcn_exp2f(x * 1.44269504088896340736f);
}
__device__ __forceinline__ float fast_sigmoid(float x){
    return __builtin_amdgcn_rcpf(1.0f + fast_exp(-x));
}
__device__ __forceinline__ float fast_tanh(float x){
    return 1.0f - 2.0f * __builtin_amdgcn_rcpf(1.0f + fast_exp(2.0f * x));
}
__device__ __forceinline__ void wsync(){
    asm volatile("s_waitcnt lgkmcnt(0)" ::: "memory");
    __builtin_amdgcn_wave_barrier();
}
// block barrier: LDS ordered, global loads may stay in flight
__device__ __forceinline__ void bar_lds(){
    asm volatile("s_waitcnt lgkmcnt(0)\n\ts_barrier" ::: "memory");
}
__device__ __forceinline__ f32x4 mfma16(uint4 a, uint4 b, f32x4 c){
    return __builtin_amdgcn_mfma_f32_16x16x32_f16(
        __builtin_bit_cast(f16x8, a), __builtin_bit_cast(f16x8, b), c, 0, 0, 0);
}
__device__ __forceinline__ uint4 load_bfrag(const float* __restrict__ W, int ldk,
                                            int o, int kk0, int kmax){
    float w[8];
    #pragma unroll
    for (int e = 0; e < 8; ++e){
        int kk = kk0 + e;
        w[e] = (kk < kmax) ? W[o*ldk + kk] : 0.f;
    }
    uint4 r;
    r.x = pack_h2f(w[0], w[1]); r.y = pack_h2f(w[2], w[3]);
    r.z = pack_h2f(w[4], w[5]); r.w = pack_h2f(w[6], w[7]);
    return r;
}

// ---------- kernel 1: attention over stations (proven) ----------
__global__ void nbst_attn(const float* __restrict__ sn, const float* __restrict__ Wn,
                          const float* __restrict__ bn, const float* __restrict__ Wa,
                          float* __restrict__ attnO){
    __shared__ float WnL[64*16];
    __shared__ float WsL[64];
    __shared__ float bnL[64];
    const int tid = threadIdx.x;
    for (int e = tid; e < 1024; e += 256) WnL[e] = Wn[e];
    if (tid < 64){ WsL[tid] = Wa[64 + tid]; bnL[tid] = bn[tid]; }
    __syncthreads();
    const int wv = tid >> 6, l = tid & 63;
    const int b = blockIdx.x * 4 + wv;
    const float* xp = sn + ((size_t)b * 64 + l) * 16;
    float x[16];
    #pragma unroll
    for (int k = 0; k < 16; ++k) x[k] = xp[k];
    float e_i = 0.f;
    for (int h = 0; h < 64; ++h){
        float acc = bnL[h];
        #pragma unroll
        for (int k = 0; k < 16; ++k) acc += x[k] * WnL[h*16 + k];
        e_i += fast_tanh(acc) * WsL[h];
    }
    float m = e_i;
    #pragma unroll
    for (int s = 32; s >= 1; s >>= 1) m = fmaxf(m, __shfl_xor(m, s));
    float p = fast_exp(e_i - m);
    float ssum = p;
    #pragma unroll
    for (int s = 32; s >= 1; s >>= 1) ssum += __shfl_xor(ssum, s);
    attnO[(size_t)b*64 + l] = p * __builtin_amdgcn_rcpf(ssum);
}

// ---------- kernel 2: persistent MLP + xg0 GEMM -> gate C-frags (proven) ----------
#define A0_CAT 0      // [64][36] u32
#define A0_H1  2304   // [64][20]
#define A0_FT  3584   // [64][68]
#define A0_WM  7936   // [8 frags][64 lanes][4]
#define A0_EMB 9984   // 260 f32
#define A0_ATT 10244  // 1024 f32
#define A0_TOT 11268

__global__ __launch_bounds__(256, 2)
void nbst_mlpxg0(const float* __restrict__ sf, const int* __restrict__ se,
                 const float* __restrict__ e0, const float* __restrict__ e1,
                 const float* __restrict__ e2, const float* __restrict__ e3,
                 const float* __restrict__ e4,
                 const float* __restrict__ Wd1, const float* __restrict__ bd1,
                 const float* __restrict__ Wd2, const float* __restrict__ bd2,
                 const float* __restrict__ Wih0, const float* __restrict__ attnI,
                 u32* __restrict__ xg0F)
{
    __shared__ u32 sm[A0_TOT];
    float* smF = reinterpret_cast<float*>(sm);
    const int tid = threadIdx.x;
    const int w = tid >> 6, l = tid & 63;
    const int q = l >> 4, c = l & 15;

    for (int e = tid; e < 260; e += 256){
        float v;
        if (e < 48)       v = e0[e];
        else if (e < 88)  v = e1[e-48];
        else if (e < 136) v = e2[e-88];
        else if (e < 164) v = e3[e-136];
        else              v = e4[e-164];
        smF[A0_EMB + e] = v;
    }
    for (int f = w; f < 8; f += 4){
        uint4 fr;
        if (f < 4){ int n = f >> 1, ks = f & 1;
                    fr = load_bfrag(Wd1, 36, 16*n + c, 32*ks + 8*q, 36); }
        else      { int n = f - 4;
                    fr = load_bfrag(Wd2, 32, 16*n + c, 8*q, 32); }
        *reinterpret_cast<uint4*>(sm + A0_WM + (f*64 + l)*4) = fr;
    }
    uint4 bw[3][4];
    #pragma unroll
    for (int nn = 0; nn < 3; ++nn)
        #pragma unroll
        for (int ks = 0; ks < 4; ++ks)
            bw[nn][ks] = load_bfrag(Wih0, 128, 16*(w + 4*nn) + c, 32*ks + 8*q, 128);
    for (int e = tid; e < 64*18; e += 256){
        int row = e / 18, j = 18 + e % 18;
        sm[A0_CAT + row*36 + j] = 0u;
    }
    const float bb10 = bd1[c],  bb11 = bd1[16+c];
    const float bb20 = bd2[c],  bb21 = bd2[16+c];
    const float bb22 = bd2[32+c], bb23 = bd2[48+c];
    __syncthreads();

    for (int tile = blockIdx.x; tile < NT_; tile += gridDim.x){
        const int gb = tile / 42, tb = tile % 42;
        for (int e = tid; e < 1024; e += 256)
            smF[A0_ATT + e] = attnI[(size_t)(16*gb)*64 + e];
        for (int e = tid; e < 64*18; e += 256){
            int row = e / 18, j = e % 18;
            int R = (16*gb + (row & 15))*S_ + 4*tb + (row >> 4);
            float c0, c1;
            if (j < 8){
                c0 = sf[(size_t)R*16 + 2*j]; c1 = sf[(size_t)R*16 + 2*j + 1];
            } else {
                int jj = j - 8, ebl = jj >> 1, d0 = (jj & 1) * 2;
                int idx = se[(size_t)R*5 + ebl] - (ebl >= 2 ? 1 : 0);
                const int toff = (ebl==0)?0:(ebl==1)?48:(ebl==2)?88:(ebl==3)?136:164;
                c0 = smF[A0_EMB + toff + idx*4 + d0];
                c1 = smF[A0_EMB + toff + idx*4 + d0 + 1];
            }
            sm[A0_CAT + row*36 + j] = pack_h2f(c0, c1);
        }
        __syncthreads();

        // P1: h1 = tanh(cat @ Wd1^T + bd1)
        {
            f32x4 c1a[2];
            c1a[0] = (f32x4){bb10, bb10, bb10, bb10};
            c1a[1] = (f32x4){bb11, bb11, bb11, bb11};
            #pragma unroll
            for (int ks = 0; ks < 2; ++ks){
                uint4 a = *reinterpret_cast<const uint4*>(
                    sm + A0_CAT + (16*w + c)*36 + ks*16 + 4*q);
                #pragma unroll
                for (int n = 0; n < 2; ++n)
                    c1a[n] = mfma16(a, *reinterpret_cast<const uint4*>(
                        sm + A0_WM + ((n*2 + ks)*64 + l)*4), c1a[n]);
            }
            #pragma unroll
            for (int n = 0; n < 2; ++n)
                #pragma unroll
                for (int j = 0; j < 4; ++j){
                    float v = fast_tanh(c1a[n][j]);
                    float vp = __shfl_xor(v, 1);
                    if (!(l & 1))
                        sm[A0_H1 + (16*w + 4*q + j)*20 + 8*n + (c >> 1)] = pack_h2f(v, vp);
                }
        }
        wsync();

        // P2: sfe = tanh(h1 @ Wd2^T + bd2); feat = [attn*sfe | sfe]
        {
            uint4 a = *reinterpret_cast<const uint4*>(
                sm + A0_H1 + (16*w + c)*20 + 4*q);
            f32x4 c2[4];
            c2[0] = (f32x4){bb20, bb20, bb20, bb20};
            c2[1] = (f32x4){bb21, bb21, bb21, bb21};
            c2[2] = (f32x4){bb22, bb22, bb22, bb22};
            c2[3] = (f32x4){bb23, bb23, bb23, bb23};
            #pragma unroll
            for (int n = 0; n < 4; ++n)
                c2[n] = mfma16(a, *reinterpret_cast<const uint4*>(
                    sm + A0_WM + ((4 + n)*64 + l)*4), c2[n]);
            #pragma unroll
            for (int n = 0; n < 4; ++n)
                #pragma unroll
                for (int j = 0; j < 4; ++j){
                    float s  = fast_tanh(c2[n][j]);
                    float fa = smF[A0_ATT + (4*q + j)*64 + 16*n + c] * s;
                    float sp  = __shfl_xor(s, 1);
                    float fap = __shfl_xor(fa, 1);
                    if (!(l & 1)){
                        int row = 16*w + 4*q + j;
                        int ci = 8*n + (c >> 1);
                        sm[A0_FT + row*68 + ci]      = pack_h2f(fa, fap);
                        sm[A0_FT + row*68 + 32 + ci] = pack_h2f(s, sp);
                    }
                }
        }
        __syncthreads();

        // P3: xg0 C-frags = feat @ Wih0^T, lane-contiguous packed stores
        #pragma unroll
        for (int m = 0; m < 4; ++m){
            uint4 af[4];
            #pragma unroll
            for (int ks = 0; ks < 4; ++ks)
                af[ks] = *reinterpret_cast<const uint4*>(
                    sm + A0_FT + (16*m + c)*68 + ks*16 + 4*q);
            f32x4 acc[3];
            #pragma unroll
            for (int nn = 0; nn < 3; ++nn) acc[nn] = (f32x4){0.f, 0.f, 0.f, 0.f};
            #pragma unroll
            for (int ks = 0; ks < 4; ++ks)
                #pragma unroll
                for (int nn = 0; nn < 3; ++nn)
                    acc[nn] = mfma16(af[ks], bw[nn][ks], acc[nn]);
            size_t base = ((size_t)(gb*S_ + 4*tb + m))*1536 + (size_t)w*384 + (size_t)l*6;
            uint2 s01, s23, s45;
            s01.x = pack_h2f(acc[0][0], acc[0][1]); s01.y = pack_h2f(acc[0][2], acc[0][3]);
            s23.x = pack_h2f(acc[1][0], acc[1][1]); s23.y = pack_h2f(acc[1][2], acc[1][3]);
            s45.x = pack_h2f(acc[2][0], acc[2][1]); s45.y = pack_h2f(acc[2][2], acc[2][3]);
            *reinterpret_cast<uint2*>(xg0F + base + 0) = s01;
            *reinterpret_cast<uint2*>(xg0F + base + 2) = s23;
            *reinterpret_cast<uint2*>(xg0F + base + 4) = s45;
        }
        __syncthreads();
    }
}

// ---------- kernel 3: FUSED GRU L0+L1+pred, 2 groups/block (2 waves/SIMD) ----------
// 512 threads: waves 0-3 = group 2*blk, waves 4-7 = group 2*blk+1.
// Co-resident independent chains hide each other's latency on each SIMD.
#define RW0 6912               // Whh0 [192][36] u32
#define RW1 13056              // [Wih1|Whh1] [192][68] u32
#define RHB (RW0 + RW1)
#define RF_TOT (RHB + 4096)    // 2 groups x (2 layers x 2 bufs x 512)

__global__ __launch_bounds__(512, 1)
void nbst_recf(const u32* __restrict__ xg0F,
               const float* __restrict__ Whh0,
               const float* __restrict__ bih0, const float* __restrict__ bhh0,
               const float* __restrict__ Wih1, const float* __restrict__ Whh1,
               const float* __restrict__ bih1, const float* __restrict__ bhh1,
               const float* __restrict__ Wpred, const float* __restrict__ bpred,
               float* __restrict__ outp)
{
    extern __shared__ u32 sm[];
    u32* smw0 = sm;
    u32* smw1 = sm + RW0;
    const int tid = threadIdx.x;
    const int w8 = tid >> 6, l = tid & 63;
    const int grp = w8 >> 2, w = w8 & 3;
    const int q = l >> 4, c = l & 15;
    const int g = blockIdx.x * 2 + grp;
    u32* HB = sm + RHB + grp * 2048;   // per-group h buffers

    for (int e = tid; e < 192*32; e += 512){
        int row = e >> 5, k = e & 31;
        smw0[row*36 + k] = pack_h2f(Whh0[row*64 + 2*k], Whh0[row*64 + 2*k + 1]);
    }
    for (int e = tid; e < 192*64; e += 512){
        int row = e / 64, kp = e % 64;
        smw1[row*68 + kp] = (kp < 32)
            ? pack_h2f(Wih1[row*64 + 2*kp],      Wih1[row*64 + 2*kp + 1])
            : pack_h2f(Whh1[row*64 + 2*(kp-32)], Whh1[row*64 + 2*(kp-32) + 1]);
    }
    for (int e = tid; e < 4096; e += 512) sm[RHB + e] = 0u;
    __syncthreads();

    const int gr = 16*w + c, gz = 64 + 16*w + c, gn = 128 + 16*w + c;
    uint4 aBR[2], aBZ[2], aBHN[2];
    #pragma unroll
    for (int ks = 0; ks < 2; ++ks){
        aBR[ks]  = *reinterpret_cast<const uint4*>(smw0 + gr*36 + 16*ks + 4*q);
        aBZ[ks]  = *reinterpret_cast<const uint4*>(smw0 + gz*36 + 16*ks + 4*q);
        aBHN[ks] = *reinterpret_cast<const uint4*>(smw0 + gn*36 + 16*ks + 4*q);
    }
    uint4 xBR[2], xBZ[2], xBXN[2], hBR[2], hBZ[2], hBHN[2];
    #pragma unroll
    for (int ks = 0; ks < 2; ++ks){
        xBR[ks] = *reinterpret_cast<const uint4*>(smw1 + gr*68 + 16*ks + 4*q);
        xBZ[ks] = *reinterpret_cast<const uint4*>(smw1 + gz*68 + 16*ks + 4*q);
        hBR[ks] = *reinterpret_cast<const uint4*>(smw1 + gr*68 + 32 + 16*ks + 4*q);
        hBZ[ks] = *reinterpret_cast<const uint4*>(smw1 + gz*68 + 32 + 16*ks + 4*q);
    }
    xBXN[0] = *reinterpret_cast<const uint4*>(smw1 + gn*68 +      4*q);
    xBXN[1] = *reinterpret_cast<const uint4*>(smw1 + gn*68 + 16 + 4*q);
    hBHN[0] = *reinterpret_cast<const uint4*>(smw1 + gn*68 + 32 + 4*q);
    hBHN[1] = *reinterpret_cast<const uint4*>(smw1 + gn*68 + 48 + 4*q);

    const float br0 = bih0[gr] + bhh0[gr], bz0 = bih0[gz] + bhh0[gz];
    const float bxn0 = bih0[gn], bhn0 = bhh0[gn];
    const float br1 = bih1[gr] + bhh1[gr], bz1 = bih1[gz] + bhh1[gz];
    const float bxn1 = bih1[gn], bhn1 = bhh1[gn];

    const int rd0 = (c*32 + 4*q)      ^ ((c & 7) << 2);
    const int rd1 = (c*32 + 4*q + 16) ^ ((c & 7) << 2);
    int wri[4];
    #pragma unroll
    for (int j = 0; j < 4; ++j){
        int row = 4*q + j;
        wri[j] = (row*64 + 16*w + c) ^ ((row & 7) << 3);
    }

    const u32* xb = xg0F + (size_t)g * S_ * 1536 + (size_t)w * 384 + (size_t)l * 6;
    uint2 x0a, x0b, x0c, x1a, x1b, x1c, x2a, x2b, x2c, x3a, x3b, x3c;
    {
        const u32* p0 = xb;
        const u32* p1 = xb + 1536;
        const u32* p2 = xb + 2*1536;
        const u32* p3 = xb + 3*1536;
        x0a = *(const uint2*)(p0+0); x0b = *(const uint2*)(p0+2); x0c = *(const uint2*)(p0+4);
        x1a = *(const uint2*)(p1+0); x1b = *(const uint2*)(p1+2); x1c = *(const uint2*)(p1+4);
        x2a = *(const uint2*)(p2+0); x2b = *(const uint2*)(p2+2); x2c = *(const uint2*)(p2+4);
        x3a = *(const uint2*)(p3+0); x3b = *(const uint2*)(p3+2); x3c = *(const uint2*)(p3+4);
    }
    float h0r0 = 0.f, h0r1 = 0.f, h0r2 = 0.f, h0r3 = 0.f;
    float h1r0 = 0.f, h1r1 = 0.f, h1r2 = 0.f, h1r3 = 0.f;
    __syncthreads();

#define RSTEP(I, XA, XB, XC, DOL1) do{                                          \
    const int i_ = (I);                                                         \
    const u32* hp0_ = HB + ((i_ + 1) & 1) * 512;                                \
    const u32* hp1_ = HB + 1024 + ((i_ + 1) & 1) * 512;                         \
    uint4 hA0a_ = *(const uint4*)(hp0_ + rd0);                                  \
    uint4 hA0b_ = *(const uint4*)(hp0_ + rd1);                                  \
    uint4 hA1a_ = *(const uint4*)(hp1_ + rd0);                                  \
    uint4 hA1b_ = *(const uint4*)(hp1_ + rd1);                                  \
    {   /* layer 0: h0(i); biases folded into accumulator init */               \
        f32x4 aRh_ = {br0,br0,br0,br0};                                         \
        f32x4 aZh_ = {bz0,bz0,bz0,bz0};                                         \
        f32x4 aHN_ = {bhn0,bhn0,bhn0,bhn0};                                     \
        aRh_ = mfma16(hA0a_, aBR[0], aRh_);  aRh_ = mfma16(hA0b_, aBR[1], aRh_);\
        aZh_ = mfma16(hA0a_, aBZ[0], aZh_);  aZh_ = mfma16(hA0b_, aBZ[1], aZh_);\
        aHN_ = mfma16(hA0a_, aBHN[0], aHN_); aHN_ = mfma16(hA0b_, aBHN[1], aHN_);\
        h2_t xR01_ = __builtin_bit_cast(h2_t, (XA).x);                          \
        h2_t xR23_ = __builtin_bit_cast(h2_t, (XA).y);                          \
        h2_t xZ01_ = __builtin_bit_cast(h2_t, (XB).x);                          \
        h2_t xZ23_ = __builtin_bit_cast(h2_t, (XB).y);                          \
        h2_t xN01_ = __builtin_bit_cast(h2_t, (XC).x);                          \
        h2_t xN23_ = __builtin_bit_cast(h2_t, (XC).y);                          \
        _Float16* hw_ = (_Float16*)(HB + (i_ & 1) * 512);                       \
        float rg_, zg_, ng_;                                                    \
        rg_ = fast_sigmoid((float)xR01_.x + aRh_[0]);                           \
        zg_ = fast_sigmoid((float)xZ01_.x + aZh_[0]);                           \
        ng_ = fast_tanh((float)xN01_.x + bxn0 + rg_*aHN_[0]);                   \
        h0r0 = (1.f - zg_)*ng_ + zg_*h0r0; hw_[wri[0]] = (_Float16)h0r0;        \
        rg_ = fast_sigmoid((float)xR01_.y + aRh_[1]);                           \
        zg_ = fast_sigmoid((float)xZ01_.y + aZh_[1]);                           \
        ng_ = fast_tanh((float)xN01_.y + bxn0 + rg_*aHN_[1]);                   \
        h0r1 = (1.f - zg_)*ng_ + zg_*h0r1; hw_[wri[1]] = (_Float16)h0r1;        \
        rg_ = fast_sigmoid((float)xR23_.x + aRh_[2]);                           \
        zg_ = fast_sigmoid((float)xZ23_.x + aZh_[2]);                           \
        ng_ = fast_tanh((float)xN23_.x + bxn0 + rg_*aHN_[2]);                   \
        h0r2 = (1.f - zg_)*ng_ + zg_*h0r2; hw_[wri[2]] = (_Float16)h0r2;        \
        rg_ = fast_sigmoid((float)xR23_.y + aRh_[3]);                           \
        zg_ = fast_sigmoid((float)xZ23_.y + aZh_[3]);                           \
        ng_ = fast_tanh((float)xN23_.y + bxn0 + rg_*aHN_[3]);                   \
        h0r3 = (1.f - zg_)*ng_ + zg_*h0r3; hw_[wri[3]] = (_Float16)h0r3;        \
    }                                                                           \
    if (DOL1){  /* layer 1: h1(i-1), x = o0(i-1) = hA0 */                       \
        f32x4 cR_  = {br1,br1,br1,br1};                                         \
        f32x4 cZ_  = {bz1,bz1,bz1,bz1};                                         \
        f32x4 cXN_ = {bxn1,bxn1,bxn1,bxn1};                                     \
        f32x4 cHN_ = {bhn1,bhn1,bhn1,bhn1};                                     \
        cR_  = mfma16(hA0a_, xBR[0], cR_);   cR_  = mfma16(hA0b_, xBR[1], cR_); \
        cZ_  = mfma16(hA0a_, xBZ[0], cZ_);   cZ_  = mfma16(hA0b_, xBZ[1], cZ_); \
        cXN_ = mfma16(hA0a_, xBXN[0], cXN_); cXN_ = mfma16(hA0b_, xBXN[1], cXN_);\
        cR_  = mfma16(hA1a_, hBR[0], cR_);   cR_  = mfma16(hA1b_, hBR[1], cR_); \
        cZ_  = mfma16(hA1a_, hBZ[0], cZ_);   cZ_  = mfma16(hA1b_, hBZ[1], cZ_); \
        cHN_ = mfma16(hA1a_, hBHN[0], cHN_); cHN_ = mfma16(hA1b_, hBHN[1], cHN_);\
        _Float16* hw_ = (_Float16*)(HB + 1024 + (i_ & 1) * 512);                \
        float rg_, zg_, ng_;                                                    \
        rg_ = fast_sigmoid(cR_[0]); zg_ = fast_sigmoid(cZ_[0]);                 \
        ng_ = fast_tanh(cXN_[0] + rg_*cHN_[0]);                                 \
        h1r0 = (1.f - zg_)*ng_ + zg_*h1r0; hw_[wri[0]] = (_Float16)h1r0;        \
        rg_ = fast_sigmoid(cR_[1]); zg_ = fast_sigmoid(cZ_[1]);                 \
        ng_ = fast_tanh(cXN_[1] + rg_*cHN_[1]);                                 \
        h1r1 = (1.f - zg_)*ng_ + zg_*h1r1; hw_[wri[1]] = (_Float16)h1r1;        \
        rg_ = fast_sigmoid(cR_[2]); zg_ = fast_sigmoid(cZ_[2]);                 \
        ng_ = fast_tanh(cXN_[2] + rg_*cHN_[2]);                                 \
        h1r2 = (1.f - zg_)*ng_ + zg_*h1r2; hw_[wri[2]] = (_Float16)h1r2;        \
        rg_ = fast_sigmoid(cR_[3]); zg_ = fast_sigmoid(cZ_[3]);                 \
        ng_ = fast_tanh(cXN_[3] + rg_*cHN_[3]);                                 \
        h1r3 = (1.f - zg_)*ng_ + zg_*h1r3; hw_[wri[3]] = (_Float16)h1r3;        \
    }                                                                           \
    {   /* reload this set for i+4 (consumed 4 iters later; no copies) */       \
        int tn_ = (i_ + 4 < S_) ? i_ + 4 : S_ - 1;                              \
        const u32* xp_ = xb + (size_t)tn_ * 1536;                               \
        (XA) = *(const uint2*)(xp_ + 0);                                        \
        (XB) = *(const uint2*)(xp_ + 2);                                        \
        (XC) = *(const uint2*)(xp_ + 4);                                        \
    }                                                                           \
    bar_lds();                                                                  \
} while(0)

    // peel first quad (i=0 has no L1)
    RSTEP(0, x0a, x0b, x0c, 0);
    RSTEP(1, x1a, x1b, x1c, 1);
    RSTEP(2, x2a, x2b, x2c, 1);
    RSTEP(3, x3a, x3b, x3c, 1);
    #pragma unroll 1
    for (int i4 = 1; i4 < 42; ++i4){
        const int ib = 4*i4;
        RSTEP(ib + 0, x0a, x0b, x0c, 1);
        RSTEP(ib + 1, x1a, x1b, x1c, 1);
        RSTEP(ib + 2, x2a, x2b, x2c, 1);
        RSTEP(ib + 3, x3a, x3b, x3c, 1);
    }
    {   // epilogue i = S_: layer 1 computes h1(167)
        const u32* hp0_ = HB + 512;           // h0(167) (167 odd -> buf1)
        const u32* hp1_ = HB + 1024 + 512;    // h1(166)
        uint4 hA0a_ = *(const uint4*)(hp0_ + rd0);
        uint4 hA0b_ = *(const uint4*)(hp0_ + rd1);
        uint4 hA1a_ = *(const uint4*)(hp1_ + rd0);
        uint4 hA1b_ = *(const uint4*)(hp1_ + rd1);
        f32x4 cR_  = {br1,br1,br1,br1};
        f32x4 cZ_  = {bz1,bz1,bz1,bz1};
        f32x4 cXN_ = {bxn1,bxn1,bxn1,bxn1};
        f32x4 cHN_ = {bhn1,bhn1,bhn1,bhn1};
        cR_  = mfma16(hA0a_, xBR[0], cR_);   cR_  = mfma16(hA0b_, xBR[1], cR_);
        cZ_  = mfma16(hA0a_, xBZ[0], cZ_);   cZ_  = mfma16(hA0b_, xBZ[1], cZ_);
        cXN_ = mfma16(hA0a_, xBXN[0], cXN_); cXN_ = mfma16(hA0b_, xBXN[1], cXN_);
        cR_  = mfma16(hA1a_, hBR[0], cR_);   cR_  = mfma16(hA1b_, hBR[1], cR_);
        cZ_  = mfma16(hA1a_, hBZ[0], cZ_);   cZ_  = mfma16(hA1b_, hBZ[1], cZ_);
        cHN_ = mfma16(hA1a_, hBHN[0], cHN_); cHN_ = mfma16(hA1b_, hBHN[1], cHN_);
        float rg_, zg_, ng_;
        rg_ = fast_sigmoid(cR_[0]); zg_ = fast_sigmoid(cZ_[0]);
        ng_ = fast_tanh(cXN_[0] + rg_*cHN_[0]);
        h1r0 = (1.f - zg_)*ng_ + zg_*h1r0;
        rg_ = fast_sigmoid(cR_[1]); zg_ = fast_sigmoid(cZ_[1]);
        ng_ = fast_tanh(cXN_[1] + rg_*cHN_[1]);
        h1r1 = (1.f - zg_)*ng_ + zg_*h1r1;
        rg_ = fast_sigmoid(cR_[2]); zg_ = fast_sigmoid(cZ_[2]);
        ng_ = fast_tanh(cXN_[2] + rg_*cHN_[2]);
        h1r2 = (1.f - zg_)*ng_ + zg_*h1r2;
        rg_ = fast_sigmoid(cR_[3]); zg_ = fast_sigmoid(cZ_[3]);
        ng_ = fast_tanh(cXN_[3] + rg_*cHN_[3]);
        h1r3 = (1.f - zg_)*ng_ + zg_*h1r3;
    }

    // ---- pred head: f32 finals via LDS scratch (weights region dead) ----
    __syncthreads();
    float* s0 = reinterpret_cast<float*>(sm);          // [32 rows][64]
    float* s1 = reinterpret_cast<float*>(sm) + 2048;   // [32 rows][64]
    #pragma unroll
    for (int j = 0; j < 4; ++j){
        int row = grp*16 + 4*q + j;
        float h0v = (j == 0) ? h0r0 : (j == 1) ? h0r1 : (j == 2) ? h0r2 : h0r3;
        float h1v = (j == 0) ? h1r0 : (j == 1) ? h1r1 : (j == 2) ? h1r2 : h1r3;
        s0[row*64 + 16*w + c] = h0v;
        s1[row*64 + 16*w + c] = h1v;
    }
    __syncthreads();
    {
        const int r = tid >> 4, cg = tid & 15;   // r in 0..31
        const float* hp0 = s0 + r*64 + 4*cg;
        const float* hp1 = s1 + r*64 + 4*cg;
        const float* wp0 = Wpred + 4*cg;
        const float* wp1 = Wpred + 64 + 4*cg;
        float part = hp0[0]*wp0[0] + hp0[1]*wp0[1] + hp0[2]*wp0[2] + hp0[3]*wp0[3]
                   + hp1[0]*wp1[0] + hp1[1]*wp1[1] + hp1[2]*wp1[2] + hp1[3]*wp1[3];
        part += __shfl_xor(part, 8);
        part += __shfl_xor(part, 4);
        part += __shfl_xor(part, 2);
        part += __shfl_xor(part, 1);
        if (cg == 0) outp[blockIdx.x*32 + r] = fast_tanh(part + bpred[0]);
    }
#undef RSTEP
}

// ---------- launcher ----------
extern "C" void kernel_launch(void* const* d_in, const int* in_sizes, int n_in,
                              void* d_out, int out_size, void* d_ws, size_t ws_size,
                              hipStream_t stream) {
    (void)in_sizes; (void)n_in; (void)out_size; (void)ws_size;
    const float* station_nodes    = (const float*)d_in[1];
    const float* station_features = (const float*)d_in[2];
    const int*   station_emb      = (const int*)d_in[3];
    const float* e0 = (const float*)d_in[4];
    const float* e1 = (const float*)d_in[5];
    const float* e2 = (const float*)d_in[6];
    const float* e3 = (const float*)d_in[7];
    const float* e4 = (const float*)d_in[8];
    const float* W_nodes = (const float*)d_in[9];
    const float* b_nodes = (const float*)d_in[10];
    const float* W_attn  = (const float*)d_in[11];
    const float* W_d1 = (const float*)d_in[13];
    const float* b_d1 = (const float*)d_in[14];
    const float* W_d2 = (const float*)d_in[15];
    const float* b_d2 = (const float*)d_in[16];
    const float* Wih0 = (const float*)d_in[17];
    const float* Whh0 = (const float*)d_in[18];
    const float* bih0 = (const float*)d_in[19];
    const float* bhh0 = (const float*)d_in[20];
    const float* Wih1 = (const float*)d_in[21];
    const float* Whh1 = (const float*)d_in[22];
    const float* bih1 = (const float*)d_in[23];
    const float* bhh1 = (const float*)d_in[24];
    const float* W_pred = (const float*)d_in[25];
    const float* b_pred = (const float*)d_in[26];
    float* outp = (float*)d_out;

    char* ws = (char*)d_ws;
    float* attnW = (float*)ws;                 // 512 KiB
    u32*   xg0F  = (u32*)(ws + (1u<<20));      // 128*168*1536 u32 = 132 MB

    hipFuncSetAttribute((const void*)nbst_recf,
                        hipFuncAttributeMaxDynamicSharedMemorySize, 112*1024);

    nbst_attn<<<dim3(512), dim3(256), 0, stream>>>(station_nodes, W_nodes, b_nodes, W_attn, attnW);
    nbst_mlpxg0<<<dim3(768), dim3(256), 0, stream>>>(
        station_features, station_emb, e0, e1, e2, e3, e4,
        W_d1, b_d1, W_d2, b_d2, Wih0, attnW, xg0F);
    nbst_recf<<<dim3(64), dim3(512), RF_TOT*4, stream>>>(
        xg0F, Whh0, bih0, bhh0, Wih1, Whh1, bih1, bhh1,
        W_pred, b_pred, outp);
}

// Round 14
// 190.081 us; speedup vs baseline: 1.3895x; 1.3895x over previous
//
#include <hip/hip_runtime.h>
#include <cstdint>
#include <cstddef>

#define B_ 2048
#define S_ 168
#define NT_ 5376   // 128 groups x 42 t-tiles

// ---------- helpers ----------
typedef _Float16 h2_t __attribute__((ext_vector_type(2)));
typedef _Float16 f16x8 __attribute__((ext_vector_type(8)));
typedef float f32x4 __attribute__((ext_vector_type(4)));
typedef unsigned int u32;

__device__ __forceinline__ unsigned pack_h2f(float a, float b){
    h2_t v; v.x = (_Float16)a; v.y = (_Float16)b;
    return __builtin_bit_cast(unsigned, v);
}
__device__ __forceinline__ float fast_exp(float x){
    return __builtin_amdgcn_exp2f(x * 1.44269504088896340736f);
}
__device__ __forceinline__ float fast_sigmoid(float x){
    return __builtin_amdgcn_rcpf(1.0f + fast_exp(-x));
}
__device__ __forceinline__ float fast_tanh(float x){
    return 1.0f - 2.0f * __builtin_amdgcn_rcpf(1.0f + fast_exp(2.0f * x));
}
__device__ __forceinline__ void wsync(){
    asm volatile("s_waitcnt lgkmcnt(0)" ::: "memory");
    __builtin_amdgcn_wave_barrier();
}
// block barrier: LDS ordered, global loads may stay in flight
__device__ __forceinline__ void bar_lds(){
    asm volatile("s_waitcnt lgkmcnt(0)\n\ts_barrier" ::: "memory");
}
__device__ __forceinline__ f32x4 mfma16(uint4 a, uint4 b, f32x4 c){
    return __builtin_amdgcn_mfma_f32_16x16x32_f16(
        __builtin_bit_cast(f16x8, a), __builtin_bit_cast(f16x8, b), c, 0, 0, 0);
}
__device__ __forceinline__ uint4 load_bfrag(const float* __restrict__ W, int ldk,
                                            int o, int kk0, int kmax){
    float w[8];
    #pragma unroll
    for (int e = 0; e < 8; ++e){
        int kk = kk0 + e;
        w[e] = (kk < kmax) ? W[o*ldk + kk] : 0.f;
    }
    uint4 r;
    r.x = pack_h2f(w[0], w[1]); r.y = pack_h2f(w[2], w[3]);
    r.z = pack_h2f(w[4], w[5]); r.w = pack_h2f(w[6], w[7]);
    return r;
}

// ---------- kernel 1: attention over stations (proven) ----------
__global__ void nbst_attn(const float* __restrict__ sn, const float* __restrict__ Wn,
                          const float* __restrict__ bn, const float* __restrict__ Wa,
                          float* __restrict__ attnO){
    __shared__ float WnL[64*16];
    __shared__ float WsL[64];
    __shared__ float bnL[64];
    const int tid = threadIdx.x;
    for (int e = tid; e < 1024; e += 256) WnL[e] = Wn[e];
    if (tid < 64){ WsL[tid] = Wa[64 + tid]; bnL[tid] = bn[tid]; }
    __syncthreads();
    const int wv = tid >> 6, l = tid & 63;
    const int b = blockIdx.x * 4 + wv;
    const float* xp = sn + ((size_t)b * 64 + l) * 16;
    float x[16];
    #pragma unroll
    for (int k = 0; k < 16; ++k) x[k] = xp[k];
    float e_i = 0.f;
    for (int h = 0; h < 64; ++h){
        float acc = bnL[h];
        #pragma unroll
        for (int k = 0; k < 16; ++k) acc += x[k] * WnL[h*16 + k];
        e_i += fast_tanh(acc) * WsL[h];
    }
    float m = e_i;
    #pragma unroll
    for (int s = 32; s >= 1; s >>= 1) m = fmaxf(m, __shfl_xor(m, s));
    float p = fast_exp(e_i - m);
    float ssum = p;
    #pragma unroll
    for (int s = 32; s >= 1; s >>= 1) ssum += __shfl_xor(ssum, s);
    attnO[(size_t)b*64 + l] = p * __builtin_amdgcn_rcpf(ssum);
}

// ---------- kernel 2: persistent MLP + xg0 GEMM -> gate C-frags (proven) ----------
#define A0_CAT 0      // [64][36] u32
#define A0_H1  2304   // [64][20]
#define A0_FT  3584   // [64][68]
#define A0_WM  7936   // [8 frags][64 lanes][4]
#define A0_EMB 9984   // 260 f32
#define A0_ATT 10244  // 1024 f32
#define A0_TOT 11268

__global__ __launch_bounds__(256, 2)
void nbst_mlpxg0(const float* __restrict__ sf, const int* __restrict__ se,
                 const float* __restrict__ e0, const float* __restrict__ e1,
                 const float* __restrict__ e2, const float* __restrict__ e3,
                 const float* __restrict__ e4,
                 const float* __restrict__ Wd1, const float* __restrict__ bd1,
                 const float* __restrict__ Wd2, const float* __restrict__ bd2,
                 const float* __restrict__ Wih0, const float* __restrict__ attnI,
                 u32* __restrict__ xg0F)
{
    __shared__ u32 sm[A0_TOT];
    float* smF = reinterpret_cast<float*>(sm);
    const int tid = threadIdx.x;
    const int w = tid >> 6, l = tid & 63;
    const int q = l >> 4, c = l & 15;

    for (int e = tid; e < 260; e += 256){
        float v;
        if (e < 48)       v = e0[e];
        else if (e < 88)  v = e1[e-48];
        else if (e < 136) v = e2[e-88];
        else if (e < 164) v = e3[e-136];
        else              v = e4[e-164];
        smF[A0_EMB + e] = v;
    }
    for (int f = w; f < 8; f += 4){
        uint4 fr;
        if (f < 4){ int n = f >> 1, ks = f & 1;
                    fr = load_bfrag(Wd1, 36, 16*n + c, 32*ks + 8*q, 36); }
        else      { int n = f - 4;
                    fr = load_bfrag(Wd2, 32, 16*n + c, 8*q, 32); }
        *reinterpret_cast<uint4*>(sm + A0_WM + (f*64 + l)*4) = fr;
    }
    uint4 bw[3][4];
    #pragma unroll
    for (int nn = 0; nn < 3; ++nn)
        #pragma unroll
        for (int ks = 0; ks < 4; ++ks)
            bw[nn][ks] = load_bfrag(Wih0, 128, 16*(w + 4*nn) + c, 32*ks + 8*q, 128);
    for (int e = tid; e < 64*18; e += 256){
        int row = e / 18, j = 18 + e % 18;
        sm[A0_CAT + row*36 + j] = 0u;
    }
    const float bb10 = bd1[c],  bb11 = bd1[16+c];
    const float bb20 = bd2[c],  bb21 = bd2[16+c];
    const float bb22 = bd2[32+c], bb23 = bd2[48+c];
    __syncthreads();

    for (int tile = blockIdx.x; tile < NT_; tile += gridDim.x){
        const int gb = tile / 42, tb = tile % 42;
        for (int e = tid; e < 1024; e += 256)
            smF[A0_ATT + e] = attnI[(size_t)(16*gb)*64 + e];
        for (int e = tid; e < 64*18; e += 256){
            int row = e / 18, j = e % 18;
            int R = (16*gb + (row & 15))*S_ + 4*tb + (row >> 4);
            float c0, c1;
            if (j < 8){
                c0 = sf[(size_t)R*16 + 2*j]; c1 = sf[(size_t)R*16 + 2*j + 1];
            } else {
                int jj = j - 8, ebl = jj >> 1, d0 = (jj & 1) * 2;
                int idx = se[(size_t)R*5 + ebl] - (ebl >= 2 ? 1 : 0);
                const int toff = (ebl==0)?0:(ebl==1)?48:(ebl==2)?88:(ebl==3)?136:164;
                c0 = smF[A0_EMB + toff + idx*4 + d0];
                c1 = smF[A0_EMB + toff + idx*4 + d0 + 1];
            }
            sm[A0_CAT + row*36 + j] = pack_h2f(c0, c1);
        }
        __syncthreads();

        // P1: h1 = tanh(cat @ Wd1^T + bd1)
        {
            f32x4 c1a[2];
            c1a[0] = (f32x4){bb10, bb10, bb10, bb10};
            c1a[1] = (f32x4){bb11, bb11, bb11, bb11};
            #pragma unroll
            for (int ks = 0; ks < 2; ++ks){
                uint4 a = *reinterpret_cast<const uint4*>(
                    sm + A0_CAT + (16*w + c)*36 + ks*16 + 4*q);
                #pragma unroll
                for (int n = 0; n < 2; ++n)
                    c1a[n] = mfma16(a, *reinterpret_cast<const uint4*>(
                        sm + A0_WM + ((n*2 + ks)*64 + l)*4), c1a[n]);
            }
            #pragma unroll
            for (int n = 0; n < 2; ++n)
                #pragma unroll
                for (int j = 0; j < 4; ++j){
                    float v = fast_tanh(c1a[n][j]);
                    float vp = __shfl_xor(v, 1);
                    if (!(l & 1))
                        sm[A0_H1 + (16*w + 4*q + j)*20 + 8*n + (c >> 1)] = pack_h2f(v, vp);
                }
        }
        wsync();

        // P2: sfe = tanh(h1 @ Wd2^T + bd2); feat = [attn*sfe | sfe]
        {
            uint4 a = *reinterpret_cast<const uint4*>(
                sm + A0_H1 + (16*w + c)*20 + 4*q);
            f32x4 c2[4];
            c2[0] = (f32x4){bb20, bb20, bb20, bb20};
            c2[1] = (f32x4){bb21, bb21, bb21, bb21};
            c2[2] = (f32x4){bb22, bb22, bb22, bb22};
            c2[3] = (f32x4){bb23, bb23, bb23, bb23};
            #pragma unroll
            for (int n = 0; n < 4; ++n)
                c2[n] = mfma16(a, *reinterpret_cast<const uint4*>(
                    sm + A0_WM + ((4 + n)*64 + l)*4), c2[n]);
            #pragma unroll
            for (int n = 0; n < 4; ++n)
                #pragma unroll
                for (int j = 0; j < 4; ++j){
                    float s  = fast_tanh(c2[n][j]);
                    float fa = smF[A0_ATT + (4*q + j)*64 + 16*n + c] * s;
                    float sp  = __shfl_xor(s, 1);
                    float fap = __shfl_xor(fa, 1);
                    if (!(l & 1)){
                        int row = 16*w + 4*q + j;
                        int ci = 8*n + (c >> 1);
                        sm[A0_FT + row*68 + ci]      = pack_h2f(fa, fap);
                        sm[A0_FT + row*68 + 32 + ci] = pack_h2f(s, sp);
                    }
                }
        }
        __syncthreads();

        // P3: xg0 C-frags = feat @ Wih0^T, lane-contiguous packed stores
        #pragma unroll
        for (int m = 0; m < 4; ++m){
            uint4 af[4];
            #pragma unroll
            for (int ks = 0; ks < 4; ++ks)
                af[ks] = *reinterpret_cast<const uint4*>(
                    sm + A0_FT + (16*m + c)*68 + ks*16 + 4*q);
            f32x4 acc[3];
            #pragma unroll
            for (int nn = 0; nn < 3; ++nn) acc[nn] = (f32x4){0.f, 0.f, 0.f, 0.f};
            #pragma unroll
            for (int ks = 0; ks < 4; ++ks)
                #pragma unroll
                for (int nn = 0; nn < 3; ++nn)
                    acc[nn] = mfma16(af[ks], bw[nn][ks], acc[nn]);
            size_t base = ((size_t)(gb*S_ + 4*tb + m))*1536 + (size_t)w*384 + (size_t)l*6;
            uint2 s01, s23, s45;
            s01.x = pack_h2f(acc[0][0], acc[0][1]); s01.y = pack_h2f(acc[0][2], acc[0][3]);
            s23.x = pack_h2f(acc[1][0], acc[1][1]); s23.y = pack_h2f(acc[1][2], acc[1][3]);
            s45.x = pack_h2f(acc[2][0], acc[2][1]); s45.y = pack_h2f(acc[2][2], acc[2][3]);
            *reinterpret_cast<uint2*>(xg0F + base + 0) = s01;
            *reinterpret_cast<uint2*>(xg0F + base + 2) = s23;
            *reinterpret_cast<uint2*>(xg0F + base + 4) = s45;
        }
        __syncthreads();
    }
}

// ---------- kernel 3: FUSED GRU, layer-split wave specialization ----------
// 128 blocks x 512 threads. Waves 0-3 (SIMDs 0-3): layer 0.
// Waves 4-7 (SIMDs 0-3): layer 1, one step behind. Each SIMD hosts one
// L0-wave + one L1-wave whose independent chains interleave.
#define RW0 6912               // Whh0 [192][36] u32
#define RW1 13056              // [Wih1|Whh1] [192][68] u32
#define RHB (RW0 + RW1)
#define RF_TOT (RHB + 2048)    // h0 dbuf (2x512) + h1 dbuf (2x512)

__global__ __launch_bounds__(512, 1)
void nbst_recf(const u32* __restrict__ xg0F,
               const float* __restrict__ Whh0,
               const float* __restrict__ bih0, const float* __restrict__ bhh0,
               const float* __restrict__ Wih1, const float* __restrict__ Whh1,
               const float* __restrict__ bih1, const float* __restrict__ bhh1,
               const float* __restrict__ Wpred, const float* __restrict__ bpred,
               float* __restrict__ outp)
{
    extern __shared__ u32 sm[];
    u32* smw0 = sm;
    u32* smw1 = sm + RW0;
    u32* HB0  = sm + RHB;          // h0: 2 x 512
    u32* HB1  = sm + RHB + 1024;   // h1: 2 x 512
    const int tid = threadIdx.x;
    const int w8 = tid >> 6, l = tid & 63;
    const int grp = w8 >> 2, w = w8 & 3;
    const int q = l >> 4, c = l & 15;
    const int g = blockIdx.x, B0 = g*16;

    for (int e = tid; e < 192*32; e += 512){
        int row = e >> 5, k = e & 31;
        smw0[row*36 + k] = pack_h2f(Whh0[row*64 + 2*k], Whh0[row*64 + 2*k + 1]);
    }
    for (int e = tid; e < 192*64; e += 512){
        int row = e / 64, kp = e % 64;
        smw1[row*68 + kp] = (kp < 32)
            ? pack_h2f(Wih1[row*64 + 2*kp],      Wih1[row*64 + 2*kp + 1])
            : pack_h2f(Whh1[row*64 + 2*(kp-32)], Whh1[row*64 + 2*(kp-32) + 1]);
    }
    for (int e = tid; e < 2048; e += 512) sm[RHB + e] = 0u;
    __syncthreads();

    const int gr = 16*w + c, gz = 64 + 16*w + c, gn = 128 + 16*w + c;
    const int rd0 = (c*32 + 4*q)      ^ ((c & 7) << 2);
    const int rd1 = (c*32 + 4*q + 16) ^ ((c & 7) << 2);
    int wri[4];
    #pragma unroll
    for (int j = 0; j < 4; ++j){
        int row = 4*q + j;
        wri[j] = (row*64 + 16*w + c) ^ ((row & 7) << 3);
    }

    float hv0 = 0.f, hv1 = 0.f, hv2 = 0.f, hv3 = 0.f;   // this wave's layer h

    if (grp == 0){
        // ================= LAYER 0 waves =================
        uint4 aBR[2], aBZ[2], aBHN[2];
        #pragma unroll
        for (int ks = 0; ks < 2; ++ks){
            aBR[ks]  = *reinterpret_cast<const uint4*>(smw0 + gr*36 + 16*ks + 4*q);
            aBZ[ks]  = *reinterpret_cast<const uint4*>(smw0 + gz*36 + 16*ks + 4*q);
            aBHN[ks] = *reinterpret_cast<const uint4*>(smw0 + gn*36 + 16*ks + 4*q);
        }
        const float br0 = bih0[gr] + bhh0[gr], bz0 = bih0[gz] + bhh0[gz];
        const float bxn0 = bih0[gn], bhn0 = bhh0[gn];

        const u32* xb = xg0F + (size_t)g * S_ * 1536 + (size_t)w * 384 + (size_t)l * 6;
        uint2 x0a, x0b, x0c, x1a, x1b, x1c, x2a, x2b, x2c, x3a, x3b, x3c;
        {
            const u32* p0 = xb;
            const u32* p1 = xb + 1536;
            const u32* p2 = xb + 2*1536;
            const u32* p3 = xb + 3*1536;
            x0a = *(const uint2*)(p0+0); x0b = *(const uint2*)(p0+2); x0c = *(const uint2*)(p0+4);
            x1a = *(const uint2*)(p1+0); x1b = *(const uint2*)(p1+2); x1c = *(const uint2*)(p1+4);
            x2a = *(const uint2*)(p2+0); x2b = *(const uint2*)(p2+2); x2c = *(const uint2*)(p2+4);
            x3a = *(const uint2*)(p3+0); x3b = *(const uint2*)(p3+2); x3c = *(const uint2*)(p3+4);
        }

#define L0STEP(I, XA, XB, XC) do{                                               \
    const int i_ = (I);                                                         \
    const u32* hp0_ = HB0 + ((i_ + 1) & 1) * 512;                               \
    uint4 hA0a_ = *(const uint4*)(hp0_ + rd0);                                  \
    uint4 hA0b_ = *(const uint4*)(hp0_ + rd1);                                  \
    f32x4 aRh_ = {br0,br0,br0,br0};                                             \
    f32x4 aZh_ = {bz0,bz0,bz0,bz0};                                             \
    f32x4 aHN_ = {bhn0,bhn0,bhn0,bhn0};                                         \
    aRh_ = mfma16(hA0a_, aBR[0], aRh_);  aRh_ = mfma16(hA0b_, aBR[1], aRh_);    \
    aZh_ = mfma16(hA0a_, aBZ[0], aZh_);  aZh_ = mfma16(hA0b_, aBZ[1], aZh_);    \
    aHN_ = mfma16(hA0a_, aBHN[0], aHN_); aHN_ = mfma16(hA0b_, aBHN[1], aHN_);   \
    h2_t xR01_ = __builtin_bit_cast(h2_t, (XA).x);                              \
    h2_t xR23_ = __builtin_bit_cast(h2_t, (XA).y);                              \
    h2_t xZ01_ = __builtin_bit_cast(h2_t, (XB).x);                              \
    h2_t xZ23_ = __builtin_bit_cast(h2_t, (XB).y);                              \
    h2_t xN01_ = __builtin_bit_cast(h2_t, (XC).x);                              \
    h2_t xN23_ = __builtin_bit_cast(h2_t, (XC).y);                              \
    _Float16* hw_ = (_Float16*)(HB0 + (i_ & 1) * 512);                          \
    float rg_, zg_, ng_;                                                        \
    rg_ = fast_sigmoid((float)xR01_.x + aRh_[0]);                               \
    zg_ = fast_sigmoid((float)xZ01_.x + aZh_[0]);                               \
    ng_ = fast_tanh((float)xN01_.x + bxn0 + rg_*aHN_[0]);                       \
    hv0 = (1.f - zg_)*ng_ + zg_*hv0; hw_[wri[0]] = (_Float16)hv0;               \
    rg_ = fast_sigmoid((float)xR01_.y + aRh_[1]);                               \
    zg_ = fast_sigmoid((float)xZ01_.y + aZh_[1]);                               \
    ng_ = fast_tanh((float)xN01_.y + bxn0 + rg_*aHN_[1]);                       \
    hv1 = (1.f - zg_)*ng_ + zg_*hv1; hw_[wri[1]] = (_Float16)hv1;               \
    rg_ = fast_sigmoid((float)xR23_.x + aRh_[2]);                               \
    zg_ = fast_sigmoid((float)xZ23_.x + aZh_[2]);                               \
    ng_ = fast_tanh((float)xN23_.x + bxn0 + rg_*aHN_[2]);                       \
    hv2 = (1.f - zg_)*ng_ + zg_*hv2; hw_[wri[2]] = (_Float16)hv2;               \
    rg_ = fast_sigmoid((float)xR23_.y + aRh_[3]);                               \
    zg_ = fast_sigmoid((float)xZ23_.y + aZh_[3]);                               \
    ng_ = fast_tanh((float)xN23_.y + bxn0 + rg_*aHN_[3]);                       \
    hv3 = (1.f - zg_)*ng_ + zg_*hv3; hw_[wri[3]] = (_Float16)hv3;               \
    {   int tn_ = (i_ + 4 < S_) ? i_ + 4 : S_ - 1;                              \
        const u32* xp_ = xb + (size_t)tn_ * 1536;                               \
        (XA) = *(const uint2*)(xp_ + 0);                                        \
        (XB) = *(const uint2*)(xp_ + 2);                                        \
        (XC) = *(const uint2*)(xp_ + 4);                                        \
    }                                                                           \
    bar_lds();                                                                  \
} while(0)

        L0STEP(0, x0a, x0b, x0c);
        L0STEP(1, x1a, x1b, x1c);
        L0STEP(2, x2a, x2b, x2c);
        L0STEP(3, x3a, x3b, x3c);
        #pragma unroll 1
        for (int i4 = 1; i4 < 42; ++i4){
            const int ib = 4*i4;
            L0STEP(ib + 0, x0a, x0b, x0c);
            L0STEP(ib + 1, x1a, x1b, x1c);
            L0STEP(ib + 2, x2a, x2b, x2c);
            L0STEP(ib + 3, x3a, x3b, x3c);
        }
        bar_lds();   // iteration i = S_ (L0 idle)
#undef L0STEP
    } else {
        // ================= LAYER 1 waves =================
        uint4 xBR[2], xBZ[2], xBXN[2], hBR[2], hBZ[2], hBHN[2];
        #pragma unroll
        for (int ks = 0; ks < 2; ++ks){
            xBR[ks] = *reinterpret_cast<const uint4*>(smw1 + gr*68 + 16*ks + 4*q);
            xBZ[ks] = *reinterpret_cast<const uint4*>(smw1 + gz*68 + 16*ks + 4*q);
            hBR[ks] = *reinterpret_cast<const uint4*>(smw1 + gr*68 + 32 + 16*ks + 4*q);
            hBZ[ks] = *reinterpret_cast<const uint4*>(smw1 + gz*68 + 32 + 16*ks + 4*q);
        }
        xBXN[0] = *reinterpret_cast<const uint4*>(smw1 + gn*68 +      4*q);
        xBXN[1] = *reinterpret_cast<const uint4*>(smw1 + gn*68 + 16 + 4*q);
        hBHN[0] = *reinterpret_cast<const uint4*>(smw1 + gn*68 + 32 + 4*q);
        hBHN[1] = *reinterpret_cast<const uint4*>(smw1 + gn*68 + 48 + 4*q);
        const float br1 = bih1[gr] + bhh1[gr], bz1 = bih1[gz] + bhh1[gz];
        const float bxn1 = bih1[gn], bhn1 = bhh1[gn];

        bar_lds();   // iteration i = 0 (L1 idle)
        #pragma unroll 1
        for (int i = 1; i <= S_; ++i){
            const u32* hp0_ = HB0 + ((i + 1) & 1) * 512;   // h0(i-1)
            const u32* hp1_ = HB1 + ((i + 1) & 1) * 512;   // h1(i-2)
            uint4 hA0a_ = *(const uint4*)(hp0_ + rd0);
            uint4 hA0b_ = *(const uint4*)(hp0_ + rd1);
            uint4 hA1a_ = *(const uint4*)(hp1_ + rd0);
            uint4 hA1b_ = *(const uint4*)(hp1_ + rd1);
            f32x4 cR_  = {br1,br1,br1,br1};
            f32x4 cZ_  = {bz1,bz1,bz1,bz1};
            f32x4 cXN_ = {bxn1,bxn1,bxn1,bxn1};
            f32x4 cHN_ = {bhn1,bhn1,bhn1,bhn1};
            cR_  = mfma16(hA0a_, xBR[0], cR_);   cR_  = mfma16(hA0b_, xBR[1], cR_);
            cZ_  = mfma16(hA0a_, xBZ[0], cZ_);   cZ_  = mfma16(hA0b_, xBZ[1], cZ_);
            cXN_ = mfma16(hA0a_, xBXN[0], cXN_); cXN_ = mfma16(hA0b_, xBXN[1], cXN_);
            cR_  = mfma16(hA1a_, hBR[0], cR_);   cR_  = mfma16(hA1b_, hBR[1], cR_);
            cZ_  = mfma16(hA1a_, hBZ[0], cZ_);   cZ_  = mfma16(hA1b_, hBZ[1], cZ_);
            cHN_ = mfma16(hA1a_, hBHN[0], cHN_); cHN_ = mfma16(hA1b_, hBHN[1], cHN_);
            _Float16* hw_ = (_Float16*)(HB1 + (i & 1) * 512);
            float rg_, zg_, ng_;
            rg_ = fast_sigmoid(cR_[0]); zg_ = fast_sigmoid(cZ_[0]);
            ng_ = fast_tanh(cXN_[0] + rg_*cHN_[0]);
            hv0 = (1.f - zg_)*ng_ + zg_*hv0; hw_[wri[0]] = (_Float16)hv0;
            rg_ = fast_sigmoid(cR_[1]); zg_ = fast_sigmoid(cZ_[1]);
            ng_ = fast_tanh(cXN_[1] + rg_*cHN_[1]);
            hv1 = (1.f - zg_)*ng_ + zg_*hv1; hw_[wri[1]] = (_Float16)hv1;
            rg_ = fast_sigmoid(cR_[2]); zg_ = fast_sigmoid(cZ_[2]);
            ng_ = fast_tanh(cXN_[2] + rg_*cHN_[2]);
            hv2 = (1.f - zg_)*ng_ + zg_*hv2; hw_[wri[2]] = (_Float16)hv2;
            rg_ = fast_sigmoid(cR_[3]); zg_ = fast_sigmoid(cZ_[3]);
            ng_ = fast_tanh(cXN_[3] + rg_*cHN_[3]);
            hv3 = (1.f - zg_)*ng_ + zg_*hv3; hw_[wri[3]] = (_Float16)hv3;
            bar_lds();
        }
    }

    // ---- pred head: f32 finals via LDS scratch (weights region dead) ----
    __syncthreads();
    float* s0 = reinterpret_cast<float*>(sm);          // [16 rows][64]
    float* s1 = reinterpret_cast<float*>(sm) + 1024;   // [16 rows][64]
    {
        float* sd = (grp == 0) ? s0 : s1;
        #pragma unroll
        for (int j = 0; j < 4; ++j){
            int row = 4*q + j;
            float hv = (j == 0) ? hv0 : (j == 1) ? hv1 : (j == 2) ? hv2 : hv3;
            sd[row*64 + 16*w + c] = hv;
        }
    }
    __syncthreads();
    if (tid < 256){
        const int r = tid >> 4, cg = tid & 15;
        const float* hp0 = s0 + r*64 + 4*cg;
        const float* hp1 = s1 + r*64 + 4*cg;
        const float* wp0 = Wpred + 4*cg;
        const float* wp1 = Wpred + 64 + 4*cg;
        float part = hp0[0]*wp0[0] + hp0[1]*wp0[1] + hp0[2]*wp0[2] + hp0[3]*wp0[3]
                   + hp1[0]*wp1[0] + hp1[1]*wp1[1] + hp1[2]*wp1[2] + hp1[3]*wp1[3];
        part += __shfl_xor(part, 8);
        part += __shfl_xor(part, 4);
        part += __shfl_xor(part, 2);
        part += __shfl_xor(part, 1);
        if (cg == 0) outp[B0 + r] = fast_tanh(part + bpred[0]);
    }
}

// ---------- launcher ----------
extern "C" void kernel_launch(void* const* d_in, const int* in_sizes, int n_in,
                              void* d_out, int out_size, void* d_ws, size_t ws_size,
                              hipStream_t stream) {
    (void)in_sizes; (void)n_in; (void)out_size; (void)ws_size;
    const float* station_nodes    = (const float*)d_in[1];
    const float* station_features = (const float*)d_in[2];
    const int*   station_emb      = (const int*)d_in[3];
    const float* e0 = (const float*)d_in[4];
    const float* e1 = (const float*)d_in[5];
    const float* e2 = (const float*)d_in[6];
    const float* e3 = (const float*)d_in[7];
    const float* e4 = (const float*)d_in[8];
    const float* W_nodes = (const float*)d_in[9];
    const float* b_nodes = (const float*)d_in[10];
    const float* W_attn  = (const float*)d_in[11];
    const float* W_d1 = (const float*)d_in[13];
    const float* b_d1 = (const float*)d_in[14];
    const float* W_d2 = (const float*)d_in[15];
    const float* b_d2 = (const float*)d_in[16];
    const float* Wih0 = (const float*)d_in[17];
    const float* Whh0 = (const float*)d_in[18];
    const float* bih0 = (const float*)d_in[19];
    const float* bhh0 = (const float*)d_in[20];
    const float* Wih1 = (const float*)d_in[21];
    const float* Whh1 = (const float*)d_in[22];
    const float* bih1 = (const float*)d_in[23];
    const float* bhh1 = (const float*)d_in[24];
    const float* W_pred = (const float*)d_in[25];
    const float* b_pred = (const float*)d_in[26];
    float* outp = (float*)d_out;

    char* ws = (char*)d_ws;
    float* attnW = (float*)ws;                 // 512 KiB
    u32*   xg0F  = (u32*)(ws + (1u<<20));      // 128*168*1536 u32 = 132 MB

    hipFuncSetAttribute((const void*)nbst_recf,
                        hipFuncAttributeMaxDynamicSharedMemorySize, 96*1024);

    nbst_attn<<<dim3(512), dim3(256), 0, stream>>>(station_nodes, W_nodes, b_nodes, W_attn, attnW);
    nbst_mlpxg0<<<dim3(768), dim3(256), 0, stream>>>(
        station_features, station_emb, e0, e1, e2, e3, e4,
        W_d1, b_d1, W_d2, b_d2, Wih0, attnW, xg0F);
    nbst_recf<<<dim3(128), dim3(512), RF_TOT*4, stream>>>(
        xg0F, Whh0, bih0, bhh0, Wih1, Whh1, bih1, bhh1,
        W_pred, b_pred, outp);
}